// Round 19
// baseline (151.150 us; speedup 1.0000x reference)
//
#include <hip/hip_runtime.h>
#include <hip/hip_bf16.h>
#include <math.h>

#define SLEN 4096
#define DH   64
#define KVB  64
#define NHEAD 32
#define QBLK 128
#define NQT   (SLEN / QBLK)  // 32
#define TILE_E (KVB * DH)    // 4096 elems per staged tile

typedef float  f32x4 __attribute__((ext_vector_type(4)));
typedef short  bf16x8 __attribute__((ext_vector_type(8)));
typedef unsigned short u16x8 __attribute__((ext_vector_type(8)));
typedef unsigned short u16x4 __attribute__((ext_vector_type(4)));
union U8 { u16x8 u; bf16x8 b; };
union U4 { unsigned d[4]; bf16x8 b; };

__device__ inline unsigned short f2bf(float f) {
    return __builtin_bit_cast(unsigned short, __float2bfloat16(f));
}
__device__ inline unsigned pk2(float lo, float hi_) {   // v_cvt_pk_bf16_f32
    return (unsigned)f2bf(lo) | ((unsigned)f2bf(hi_) << 16);
}

__device__ inline void gload16(const unsigned short* g, unsigned short* l) {
    __builtin_amdgcn_global_load_lds(
        (const __attribute__((address_space(1))) void*)g,
        (__attribute__((address_space(3))) void*)l, 16, 0, 0);
}

// ---------------- pre-pass: f32 K,V -> bf16 swizzled tile layout in ws ----------
// K tile (4096 bf16): elem = row*64 + (d ^ ((row&7)<<3)),      row = kv, d = dim.
// V tile (4096 bf16): elem = d*64 + (pos(kk) ^ ((d&7)<<3)),    rows = dim.
//   pos(kk) = (kk>>5)*32 + ((kk&15)>>2)*8 + ((kk>>4)&1)*4 + (kk&3)
//   -> lane l4's b128 at pos l4*8 covers kk {l4*4+j} then {16+l4*4+j}: matches
//      the in-register P fragment slot order (A/B slot permutations agree).
extern "C" __global__ __launch_bounds__(512)
void prep_kv(const float* __restrict__ K, const float* __restrict__ V,
             unsigned short* __restrict__ Kb, unsigned short* __restrict__ Vt)
{
    const int tile = blockIdx.x & 63;
    const int head = blockIdx.x >> 6;
    const size_t gbase = (size_t)head * SLEN * DH + (size_t)tile * KVB * DH;
    const size_t tbase = ((size_t)head * 64 + tile) * TILE_E;
    const int tid = threadIdx.x;
    if (blockIdx.y == 0) {
        const int row = tid >> 3, d0 = (tid & 7) * 8;
        const float* src = K + gbase + (size_t)row * DH + d0;
        f32x4 a = *(const f32x4*)src, b = *(const f32x4*)(src + 4);
        u16x8 o;
        #pragma unroll
        for (int j = 0; j < 4; ++j) { o[j] = f2bf(a[j]); o[4 + j] = f2bf(b[j]); }
        *(u16x8*)&Kb[tbase + row * 64 + ((unsigned)d0 ^ ((row & 7) << 3))] = o;
    } else {
        const int kk = tid & 63, d0 = (tid >> 6) * 8;
        const int pos = ((kk >> 5) << 5) | (((kk & 15) >> 2) << 3)
                      | (((kk >> 4) & 1) << 2) | (kk & 3);
        const float* src = V + gbase + (size_t)kk * DH + d0;
        f32x4 a = *(const f32x4*)src, b = *(const f32x4*)(src + 4);
        #pragma unroll
        for (int j = 0; j < 8; ++j) {
            const int d = d0 + j;
            const float x = (j < 4) ? a[j] : b[j - 4];
            Vt[tbase + d * 64 + ((unsigned)pos ^ ((d & 7) << 3))] = f2bf(x);
        }
    }
}

// ---- main v19: v18 + K 3-buf / V 2-buf (40 KB -> 4 blocks/CU), vmcnt(2) ----
extern "C" __global__ __launch_bounds__(256, 4)
void fa_fwd_v19(const float* __restrict__ Q, float* __restrict__ O,
                const unsigned short* __restrict__ Kb,
                const unsigned short* __restrict__ Vt)
{
    const int tid  = threadIdx.x;
    const int lane = tid & 63;
    const int w    = tid >> 6;
    const int l15  = lane & 15;
    const int l4   = lane >> 4;

    // residency-balanced qt map (4 co-resident blocks per CU sum to 62)
    const int bid  = (int)blockIdx.x;
    const int i32  = bid >> 5;
    const int qt   = (i32 < 16) ? (2 * i32) : (63 - 2 * i32);
    const int head = bid & 31;                 // 4 heads/XCD -> KV L2-resident
    const size_t qbase  = (size_t)head * SLEN * DH;
    const size_t kvbase = (size_t)head * 64 * TILE_E;

    __shared__ __align__(16) unsigned short Kl[3][TILE_E];   // 24 KB
    __shared__ __align__(16) unsigned short Vl[2][TILE_E];   // 16 KB

    const float QSC = 0.125f * 1.44269504088896340736f;   // 1/sqrt(64)*log2(e)

    U8 ones;
    #pragma unroll
    for (int j = 0; j < 8; ++j) ones.u[j] = 0x3F80;       // bf16 1.0

    const unsigned short* ksrc = Kb + kvbase;
    const unsigned short* vsrc = Vt + kvbase;

    const int q0   = qt * QBLK;
    const int ntl  = 2 * qt + 2;
    // interleaved q-groups (v18): group1 live in all epochs for every wave
    const int wg0  = q0 + w * 16;
    const int wg1  = q0 + 64 + w * 16;
    const int qg0  = wg0 + l15;
    const int qg1  = wg1 + l15;

    auto stageK = [&](int b, int t) {
        const size_t toff = (size_t)t * TILE_E;
        const int ib = w * 2;
        gload16(ksrc + toff + ib * 512 + lane * 8,       &Kl[b][ib * 512]);
        gload16(ksrc + toff + (ib + 1) * 512 + lane * 8, &Kl[b][(ib + 1) * 512]);
    };
    auto stageV = [&](int b, int t) {
        const size_t toff = (size_t)t * TILE_E;
        const int ib = w * 2;
        gload16(vsrc + toff + ib * 512 + lane * 8,       &Vl[b][ib * 512]);
        gload16(vsrc + toff + (ib + 1) * 512 + lane * 8, &Vl[b][(ib + 1) * 512]);
    };

    // prologue queue (oldest->newest): K0(2), V0(2), K1(2)   (ntl >= 2 always)
    stageK(0, 0);
    stageV(0, 0);
    stageK(1, 1);

    // Q fragments for both groups (B-operand: lane holds Q[q][d = l4*8 + j])
    bf16x8 aq0[2], aq1[2];
    {
        const float* qp0 = Q + qbase + (size_t)qg0 * DH + l4 * 8;
        const float* qp1 = Q + qbase + (size_t)qg1 * DH + l4 * 8;
        #pragma unroll
        for (int ch = 0; ch < 2; ++ch) {
            f32x4 f0 = *(const f32x4*)(qp0 + ch * 32);
            f32x4 f1 = *(const f32x4*)(qp0 + ch * 32 + 4);
            U4 u;
            u.d[0] = pk2(f0[0] * QSC, f0[1] * QSC);
            u.d[1] = pk2(f0[2] * QSC, f0[3] * QSC);
            u.d[2] = pk2(f1[0] * QSC, f1[1] * QSC);
            u.d[3] = pk2(f1[2] * QSC, f1[3] * QSC);
            aq0[ch] = u.b;
            f0 = *(const f32x4*)(qp1 + ch * 32);
            f1 = *(const f32x4*)(qp1 + ch * 32 + 4);
            u.d[0] = pk2(f0[0] * QSC, f0[1] * QSC);
            u.d[1] = pk2(f0[2] * QSC, f0[3] * QSC);
            u.d[2] = pk2(f1[0] * QSC, f1[1] * QSC);
            u.d[3] = pk2(f1[2] * QSC, f1[3] * QSC);
            aq1[ch] = u.b;
        }
    }

    f32x4 acc0[4] = {}, acc1[4] = {};
    f32x4 lrow0 = {}, lrow1 = {};

    int kb = 0, vb = 0;
    for (int t = 0; t < ntl; ++t) {
        const int k0 = t * KVB;
        // queue at top: [K(t)2, V(t)2, K(t+1)2] -> wait own K+V, leave K(t+1)
        if (t + 1 < ntl) asm volatile("s_waitcnt vmcnt(2)" ::: "memory");
        else             asm volatile("s_waitcnt vmcnt(0)" ::: "memory");
        __builtin_amdgcn_s_barrier();

        // issue next stages immediately (max slack): V 1-deep, K 2-deep.
        // Targets were last read at tile t-1; their readers passed this barrier.
        if (t + 1 < ntl) stageV(vb ^ 1, t + 1);
        if (t + 2 < ntl) stageK((kb == 0) ? 2 : kb - 1, t + 2);   // (t+2)%3

        {
            const bool live0 = (k0 <= wg0 + 15);   // group1 live in all epochs
            const unsigned short* Kc = &Kl[kb][0];
            const unsigned short* Vc = &Vl[vb][0];

            // ---- swapped QK^T: D[kk][q]; K reads shared by both q-groups ----
            __builtin_amdgcn_s_setprio(1);
            f32x4 s0[4], s1[4];
            #pragma unroll
            for (int nt = 0; nt < 4; ++nt) {
                const int row = nt * 16 + l15;
                const unsigned rb = (unsigned)row * 64, sw = (unsigned)((row & 7) << 3);
                U8 ak0, ak1;
                ak0.u = *(const u16x8*)&Kc[rb + ((unsigned)(l4 * 8) ^ sw)];
                ak1.u = *(const u16x8*)&Kc[rb + ((unsigned)(32 + l4 * 8) ^ sw)];
                if (live0) {
                    f32x4 z = {};
                    z = __builtin_amdgcn_mfma_f32_16x16x32_bf16(ak0.b, aq0[0], z, 0, 0, 0);
                    s0[nt] = __builtin_amdgcn_mfma_f32_16x16x32_bf16(ak1.b, aq0[1], z, 0, 0, 0);
                }
                f32x4 z1 = {};
                z1 = __builtin_amdgcn_mfma_f32_16x16x32_bf16(ak0.b, aq1[0], z1, 0, 0, 0);
                s1[nt] = __builtin_amdgcn_mfma_f32_16x16x32_bf16(ak1.b, aq1[1], z1, 0, 0, 0);
            }
            __builtin_amdgcn_s_setprio(0);

            // ---- causal mask (per-group diagonal region) ----
            if (live0 && (k0 + KVB - 1 > wg0)) {
                #pragma unroll
                for (int nt = 0; nt < 4; ++nt)
                    #pragma unroll
                    for (int r = 0; r < 4; ++r)
                        if (k0 + nt * 16 + l4 * 4 + r > qg0) s0[nt][r] = -INFINITY;
            }
            if (k0 + KVB - 1 > wg1) {
                #pragma unroll
                for (int nt = 0; nt < 4; ++nt)
                    #pragma unroll
                    for (int r = 0; r < 4; ++r)
                        if (k0 + nt * 16 + l4 * 4 + r > qg1) s1[nt][r] = -INFINITY;
            }

            // ---- P = exp2(s) packed into slot-permuted A-frags (lane-local) ----
            U4 u00, u01, u10, u11;
            if (live0) {
                u00.d[0] = pk2(exp2f(s0[0][0]), exp2f(s0[0][1]));
                u00.d[1] = pk2(exp2f(s0[0][2]), exp2f(s0[0][3]));
                u00.d[2] = pk2(exp2f(s0[1][0]), exp2f(s0[1][1]));
                u00.d[3] = pk2(exp2f(s0[1][2]), exp2f(s0[1][3]));
                u01.d[0] = pk2(exp2f(s0[2][0]), exp2f(s0[2][1]));
                u01.d[1] = pk2(exp2f(s0[2][2]), exp2f(s0[2][3]));
                u01.d[2] = pk2(exp2f(s0[3][0]), exp2f(s0[3][1]));
                u01.d[3] = pk2(exp2f(s0[3][2]), exp2f(s0[3][3]));
            }
            u10.d[0] = pk2(exp2f(s1[0][0]), exp2f(s1[0][1]));
            u10.d[1] = pk2(exp2f(s1[0][2]), exp2f(s1[0][3]));
            u10.d[2] = pk2(exp2f(s1[1][0]), exp2f(s1[1][1]));
            u10.d[3] = pk2(exp2f(s1[1][2]), exp2f(s1[1][3]));
            u11.d[0] = pk2(exp2f(s1[2][0]), exp2f(s1[2][1]));
            u11.d[1] = pk2(exp2f(s1[2][2]), exp2f(s1[2][3]));
            u11.d[2] = pk2(exp2f(s1[3][0]), exp2f(s1[3][1]));
            u11.d[3] = pk2(exp2f(s1[3][2]), exp2f(s1[3][3]));

            // ---- PV + row-sum; V reads shared by both q-groups ----
            __builtin_amdgcn_s_setprio(1);
            if (live0) {
                lrow0 = __builtin_amdgcn_mfma_f32_16x16x32_bf16(u00.b, ones.b, lrow0, 0, 0, 0);
                lrow0 = __builtin_amdgcn_mfma_f32_16x16x32_bf16(u01.b, ones.b, lrow0, 0, 0, 0);
            }
            lrow1 = __builtin_amdgcn_mfma_f32_16x16x32_bf16(u10.b, ones.b, lrow1, 0, 0, 0);
            lrow1 = __builtin_amdgcn_mfma_f32_16x16x32_bf16(u11.b, ones.b, lrow1, 0, 0, 0);
            #pragma unroll
            for (int nt = 0; nt < 4; ++nt) {
                const int row = nt * 16 + l15;
                const unsigned rb = (unsigned)row * 64, sw = (unsigned)((row & 7) << 3);
                U8 vb0, vb1;
                vb0.u = *(const u16x8*)&Vc[rb + ((unsigned)(l4 * 8) ^ sw)];
                vb1.u = *(const u16x8*)&Vc[rb + ((unsigned)(32 + l4 * 8) ^ sw)];
                if (live0) {
                    acc0[nt] = __builtin_amdgcn_mfma_f32_16x16x32_bf16(u00.b, vb0.b, acc0[nt], 0, 0, 0);
                    acc0[nt] = __builtin_amdgcn_mfma_f32_16x16x32_bf16(u01.b, vb1.b, acc0[nt], 0, 0, 0);
                }
                acc1[nt] = __builtin_amdgcn_mfma_f32_16x16x32_bf16(u10.b, vb0.b, acc1[nt], 0, 0, 0);
                acc1[nt] = __builtin_amdgcn_mfma_f32_16x16x32_bf16(u11.b, vb1.b, acc1[nt], 0, 0, 0);
            }
            __builtin_amdgcn_s_setprio(0);
        }

        kb = (kb == 2) ? 0 : kb + 1;
        vb ^= 1;
    }

    // ---- epilogue: O = acc / lrow (row layout, no shuffles) ----
    #pragma unroll
    for (int r = 0; r < 4; ++r) {
        const float inv0 = 1.f / lrow0[r];
        const float inv1 = 1.f / lrow1[r];
        float* op0 = O + qbase + (size_t)(wg0 + l4 * 4 + r) * DH + l15;
        float* op1 = O + qbase + (size_t)(wg1 + l4 * 4 + r) * DH + l15;
        #pragma unroll
        for (int nt = 0; nt < 4; ++nt) {
            op0[nt * 16] = acc0[nt][r] * inv0;
            op1[nt * 16] = acc1[nt][r] * inv1;
        }
    }
}

// ---------------- fallback (round-4 kernel, used if ws too small) ----------------
#define QBLK4 128
#define KPAD 72
#define NQT4  (SLEN/QBLK4)
#define NPAIR4 (NQT4/2)

extern "C" __global__ __launch_bounds__(256)
void fa_fwd_causal(const float* __restrict__ Q, const float* __restrict__ K,
                   const float* __restrict__ V, float* __restrict__ O)
{
    const int tid  = threadIdx.x;
    const int lane = tid & 63;
    const int w    = tid >> 6;
    const int l15  = lane & 15;
    const int l4   = lane >> 4;

    const int bid  = (int)blockIdx.x;
    const int work = (bid & 7) * (NPAIR4 * NHEAD / 8) + (bid >> 3);
    const int head = work >> 4;
    const int pr   = work & (NPAIR4 - 1);
    const size_t base = (size_t)head * SLEN * DH;

    __shared__ unsigned short Kl[2][KVB * KPAD];
    __shared__ unsigned short Vt[2][DH * KPAD];
    __shared__ unsigned short Plds[4][16 * KPAD];

    const float QSC = 0.125f * 1.44269504088896340736f;
    const int krow = tid >> 2,        kc0 = (tid & 3) * 16;
    const int vd0  = (tid >> 4) * 4,  vk0 = (tid & 15) * 4;

    #pragma unroll 1
    for (int ph = 0; ph < 2; ++ph) {
        const int qt  = ph ? (NQT4 - 1 - pr) : pr;
        const int q0  = qt * QBLK4;
        const int ntl = 2 * qt + 2;
        const int qwave = q0 + w * 32;

        bf16x8 aq[2][2];
        #pragma unroll
        for (int set = 0; set < 2; ++set) {
            const int qr = q0 + w * 32 + set * 16 + l15;
            const float* qp = Q + base + (size_t)qr * DH + l4 * 8;
            #pragma unroll
            for (int ch = 0; ch < 2; ++ch) {
                f32x4 f0 = *(const f32x4*)(qp + ch * 32);
                f32x4 f1 = *(const f32x4*)(qp + ch * 32 + 4);
                U8 u;
                #pragma unroll
                for (int j = 0; j < 4; ++j) { u.u[j] = f2bf(f0[j] * QSC); u.u[4 + j] = f2bf(f1[j] * QSC); }
                aq[set][ch] = u.b;
            }
        }

        f32x4 acc[2][4] = {};
        float mrun[2] = { -INFINITY, -INFINITY };
        float lrun[2] = { 0.f, 0.f };
        f32x4 kreg[4], vreg[4];

        auto g_load = [&](int t) {
            const float* kp = K + base + (size_t)(t * KVB + krow) * DH + kc0;
            #pragma unroll
            for (int i = 0; i < 4; ++i) kreg[i] = *(const f32x4*)(kp + i * 4);
            const float* vp = V + base + (size_t)(t * KVB + vk0) * DH + vd0;
            #pragma unroll
            for (int i = 0; i < 4; ++i) vreg[i] = *(const f32x4*)(vp + (size_t)i * DH);
        };
        auto s_write = [&](int c) {
            unsigned short tmp[16];
            #pragma unroll
            for (int i = 0; i < 4; ++i)
                #pragma unroll
                for (int j = 0; j < 4; ++j) tmp[i * 4 + j] = f2bf(kreg[i][j]);
            unsigned short* kd = &Kl[c][krow * KPAD + kc0];
            *(u16x8*)kd       = *(u16x8*)&tmp[0];
            *(u16x8*)(kd + 8) = *(u16x8*)&tmp[8];
            #pragma unroll
            for (int i = 0; i < 4; ++i) {
                u16x4 pk;
                pk[0] = f2bf(vreg[0][i]); pk[1] = f2bf(vreg[1][i]);
                pk[2] = f2bf(vreg[2][i]); pk[3] = f2bf(vreg[3][i]);
                *(u16x4*)&Vt[c][(vd0 + i) * KPAD + vk0] = pk;
            }
        };

        g_load(0); s_write(0); g_load(1);
        __syncthreads();

        for (int t = 0; t < ntl; ++t) {
            const int c  = t & 1;
            const int k0 = t * KVB;
            if (t + 1 < ntl) { s_write(c ^ 1); if (t + 2 < ntl) g_load(t + 2); }

            if (k0 <= qwave + 31) {
                #pragma unroll
                for (int set = 0; set < 2; ++set) {
                    const int qs0 = qwave + set * 16;
                    if (k0 > qs0 + 15) continue;
                    const int q = qs0 + l15;

                    f32x4 s[4];
                    #pragma unroll
                    for (int nt = 0; nt < 4; ++nt) {
                        U8 ak0, ak1;
                        ak0.u = *(const u16x8*)&Kl[c][(nt*16 + l15) * KPAD + l4*8];
                        ak1.u = *(const u16x8*)&Kl[c][(nt*16 + l15) * KPAD + 32 + l4*8];
                        f32x4 z = {};
                        z = __builtin_amdgcn_mfma_f32_16x16x32_bf16(ak0.b, aq[set][0], z, 0, 0, 0);
                        z = __builtin_amdgcn_mfma_f32_16x16x32_bf16(ak1.b, aq[set][1], z, 0, 0, 0);
                        s[nt] = z;
                    }
                    if (k0 + KVB - 1 > qs0) {
                        #pragma unroll
                        for (int nt = 0; nt < 4; ++nt)
                            #pragma unroll
                            for (int r = 0; r < 4; ++r)
                                if (k0 + nt*16 + l4*4 + r > q) s[nt][r] = -INFINITY;
                    }
                    float mx = s[0][0];
                    #pragma unroll
                    for (int nt = 0; nt < 4; ++nt)
                        #pragma unroll
                        for (int r = 0; r < 4; ++r)
                            if (!(nt == 0 && r == 0)) mx = fmaxf(mx, s[nt][r]);
                    mx = fmaxf(mx, __shfl_xor(mx, 16));
                    mx = fmaxf(mx, __shfl_xor(mx, 32));
                    float mn = fmaxf(mrun[set], mx);
                    float fr = exp2f(mrun[set] - mn);
                    mrun[set] = mn;
                    float p[4][4];
                    float rs = 0.f;
                    #pragma unroll
                    for (int nt = 0; nt < 4; ++nt)
                        #pragma unroll
                        for (int r = 0; r < 4; ++r) {
                            float e = exp2f(s[nt][r] - mn);
                            p[nt][r] = e; rs += e;
                        }
                    rs += __shfl_xor(rs, 16);
                    rs += __shfl_xor(rs, 32);
                    lrun[set] = lrun[set] * fr + rs;

                    unsigned short* Pw = &Plds[w][0];
                    #pragma unroll
                    for (int nt = 0; nt < 4; ++nt) {
                        u16x4 pk;
                        pk[0] = f2bf(p[nt][0]); pk[1] = f2bf(p[nt][1]);
                        pk[2] = f2bf(p[nt][2]); pk[3] = f2bf(p[nt][3]);
                        *(u16x4*)&Pw[l15 * KPAD + nt*16 + l4*4] = pk;
                    }
                    #pragma unroll
                    for (int r = 0; r < 4; ++r) {
                        float frr = __shfl(fr, l4*4 + r);
                        #pragma unroll
                        for (int nt = 0; nt < 4; ++nt) acc[set][nt][r] *= frr;
                    }
                    asm volatile("s_waitcnt lgkmcnt(0)" ::: "memory");
                    __builtin_amdgcn_sched_barrier(0);
                    U8 pa0, pa1;
                    pa0.u = *(const u16x8*)&Pw[l15 * KPAD + l4*8];
                    pa1.u = *(const u16x8*)&Pw[l15 * KPAD + 32 + l4*8];
                    #pragma unroll
                    for (int nt = 0; nt < 4; ++nt) {
                        U8 vb0, vb1;
                        vb0.u = *(const u16x8*)&Vt[c][(nt*16 + l15) * KPAD + l4*8];
                        vb1.u = *(const u16x8*)&Vt[c][(nt*16 + l15) * KPAD + 32 + l4*8];
                        acc[set][nt] = __builtin_amdgcn_mfma_f32_16x16x32_bf16(pa0.b, vb0.b, acc[set][nt], 0, 0, 0);
                        acc[set][nt] = __builtin_amdgcn_mfma_f32_16x16x32_bf16(pa1.b, vb1.b, acc[set][nt], 0, 0, 0);
                    }
                }
            }
            __syncthreads();
        }
        #pragma unroll
        for (int set = 0; set < 2; ++set) {
            float inv = 1.f / lrun[set];
            #pragma unroll
            for (int r = 0; r < 4; ++r) {
                float invr = __shfl(inv, l4*4 + r);
                const int qrow = q0 + w*32 + set*16 + l4*4 + r;
                float* op = O + base + (size_t)qrow * DH + l15;
                #pragma unroll
                for (int nt = 0; nt < 4; ++nt)
                    op[nt*16] = acc[set][nt][r] * invr;
            }
        }
        __syncthreads();
    }
}

extern "C" void kernel_launch(void* const* d_in, const int* in_sizes, int n_in,
                              void* d_out, int out_size, void* d_ws, size_t ws_size,
                              hipStream_t stream) {
    (void)in_sizes; (void)n_in; (void)out_size;
    const float* q = (const float*)d_in[0];
    const float* k = (const float*)d_in[1];
    const float* v = (const float*)d_in[2];
    float* o = (float*)d_out;

    const size_t kv_elems = (size_t)NHEAD * 64 * TILE_E;
    const size_t need = 2 * kv_elems * sizeof(unsigned short);
    if (ws_size >= need) {
        unsigned short* Kb = (unsigned short*)d_ws;
        unsigned short* Vtw = Kb + kv_elems;
        prep_kv<<<dim3(NHEAD * 64, 2), 512, 0, stream>>>(k, v, Kb, Vtw);
        fa_fwd_v19<<<dim3(NQT * NHEAD), 256, 0, stream>>>(q, o, Kb, Vtw);
    } else {
        fa_fwd_causal<<<dim3(NPAIR4 * NHEAD), 256, 0, stream>>>(q, k, v, o);
    }
}

// Round 20
// 129.656 us; speedup vs baseline: 1.1658x; 1.1658x over previous
//
#include <hip/hip_runtime.h>
#include <hip/hip_bf16.h>
#include <math.h>

#define SLEN 4096
#define DH   64
#define KVB  64
#define NHEAD 32
#define QBLK 128
#define NQT   (SLEN / QBLK)  // 32
#define TILE_E (KVB * DH)    // 4096 elems per staged tile

typedef float  f32x4 __attribute__((ext_vector_type(4)));
typedef short  bf16x8 __attribute__((ext_vector_type(8)));
typedef unsigned short u16x8 __attribute__((ext_vector_type(8)));
typedef unsigned short u16x4 __attribute__((ext_vector_type(4)));
union U8 { u16x8 u; bf16x8 b; };
union U4 { unsigned d[4]; bf16x8 b; };

__device__ inline unsigned short f2bf(float f) {
    return __builtin_bit_cast(unsigned short, __float2bfloat16(f));
}
__device__ inline unsigned pk2(float lo, float hi_) {   // v_cvt_pk_bf16_f32
    return (unsigned)f2bf(lo) | ((unsigned)f2bf(hi_) << 16);
}

__device__ inline void gload16(const unsigned short* g, unsigned short* l) {
    __builtin_amdgcn_global_load_lds(
        (const __attribute__((address_space(1))) void*)g,
        (__attribute__((address_space(3))) void*)l, 16, 0, 0);
}

// ---------------- pre-pass: f32 K,V -> bf16 swizzled tile layout in ws ----------
// K tile (4096 bf16): elem = row*64 + (d ^ ((row&7)<<3)),      row = kv, d = dim.
// V tile (4096 bf16): elem = d*64 + (pos(kk) ^ ((d&7)<<3)),    rows = dim.
//   pos(kk) = (kk>>5)*32 + ((kk&15)>>2)*8 + ((kk>>4)&1)*4 + (kk&3)
//   -> lane l4's b128 at pos l4*8 covers kk {l4*4+j} then {16+l4*4+j}: matches
//      the in-register P fragment slot order (A/B slot permutations agree).
extern "C" __global__ __launch_bounds__(512)
void prep_kv(const float* __restrict__ K, const float* __restrict__ V,
             unsigned short* __restrict__ Kb, unsigned short* __restrict__ Vt)
{
    const int tile = blockIdx.x & 63;
    const int head = blockIdx.x >> 6;
    const size_t gbase = (size_t)head * SLEN * DH + (size_t)tile * KVB * DH;
    const size_t tbase = ((size_t)head * 64 + tile) * TILE_E;
    const int tid = threadIdx.x;
    if (blockIdx.y == 0) {
        const int row = tid >> 3, d0 = (tid & 7) * 8;
        const float* src = K + gbase + (size_t)row * DH + d0;
        f32x4 a = *(const f32x4*)src, b = *(const f32x4*)(src + 4);
        u16x8 o;
        #pragma unroll
        for (int j = 0; j < 4; ++j) { o[j] = f2bf(a[j]); o[4 + j] = f2bf(b[j]); }
        *(u16x8*)&Kb[tbase + row * 64 + ((unsigned)d0 ^ ((row & 7) << 3))] = o;
    } else {
        const int kk = tid & 63, d0 = (tid >> 6) * 8;
        const int pos = ((kk >> 5) << 5) | (((kk & 15) >> 2) << 3)
                      | (((kk >> 4) & 1) << 2) | (kk & 3);
        const float* src = V + gbase + (size_t)kk * DH + d0;
        f32x4 a = *(const f32x4*)src, b = *(const f32x4*)(src + 4);
        #pragma unroll
        for (int j = 0; j < 8; ++j) {
            const int d = d0 + j;
            const float x = (j < 4) ? a[j] : b[j - 4];
            Vt[tbase + d * 64 + ((unsigned)pos ^ ((d & 7) << 3))] = f2bf(x);
        }
    }
}

// ---- main v20 (= v18 champion): 3-buf, vmcnt(4), balanced map, interleaved ----
extern "C" __global__ __launch_bounds__(256, 3)
void fa_fwd_v20(const float* __restrict__ Q, float* __restrict__ O,
                const unsigned short* __restrict__ Kb,
                const unsigned short* __restrict__ Vt)
{
    const int tid  = threadIdx.x;
    const int lane = tid & 63;
    const int w    = tid >> 6;
    const int l15  = lane & 15;
    const int l4   = lane >> 4;

    // residency-balanced qt map (v16-proven)
    const int bid  = (int)blockIdx.x;
    const int i32  = bid >> 5;
    const int qt   = (i32 < 16) ? (2 * i32) : (63 - 2 * i32);
    const int head = bid & 31;                 // 4 heads/XCD -> KV L2-resident
    const size_t qbase  = (size_t)head * SLEN * DH;
    const size_t kvbase = (size_t)head * 64 * TILE_E;

    __shared__ __align__(16) unsigned short Kl[3][TILE_E];   // 8 KB each
    __shared__ __align__(16) unsigned short Vl[3][TILE_E];   // 8 KB each

    const float QSC = 0.125f * 1.44269504088896340736f;   // 1/sqrt(64)*log2(e)

    U8 ones;
    #pragma unroll
    for (int j = 0; j < 8; ++j) ones.u[j] = 0x3F80;       // bf16 1.0

    const unsigned short* ksrc = Kb + kvbase;
    const unsigned short* vsrc = Vt + kvbase;

    const int q0   = qt * QBLK;
    const int ntl  = 2 * qt + 2;
    // interleaved groups: group0 from lower half, group1 from upper half.
    const int wg0  = q0 + w * 16;
    const int wg1  = q0 + 64 + w * 16;
    const int qg0  = wg0 + l15;
    const int qg1  = wg1 + l15;

    auto stage = [&](int b, int t) {
        const size_t toff = (size_t)t * TILE_E;
        const int ib = w * 2;
        gload16(ksrc + toff + ib * 512 + lane * 8,       &Kl[b][ib * 512]);
        gload16(ksrc + toff + (ib + 1) * 512 + lane * 8, &Kl[b][(ib + 1) * 512]);
        gload16(vsrc + toff + ib * 512 + lane * 8,       &Vl[b][ib * 512]);
        gload16(vsrc + toff + (ib + 1) * 512 + lane * 8, &Vl[b][(ib + 1) * 512]);
    };

    // Q fragments for both groups (B-operand: lane holds Q[q][d = l4*8 + j])
    bf16x8 aq0[2], aq1[2];
    {
        const float* qp0 = Q + qbase + (size_t)qg0 * DH + l4 * 8;
        const float* qp1 = Q + qbase + (size_t)qg1 * DH + l4 * 8;
        #pragma unroll
        for (int ch = 0; ch < 2; ++ch) {
            f32x4 f0 = *(const f32x4*)(qp0 + ch * 32);
            f32x4 f1 = *(const f32x4*)(qp0 + ch * 32 + 4);
            U4 u;
            u.d[0] = pk2(f0[0] * QSC, f0[1] * QSC);
            u.d[1] = pk2(f0[2] * QSC, f0[3] * QSC);
            u.d[2] = pk2(f1[0] * QSC, f1[1] * QSC);
            u.d[3] = pk2(f1[2] * QSC, f1[3] * QSC);
            aq0[ch] = u.b;
            f0 = *(const f32x4*)(qp1 + ch * 32);
            f1 = *(const f32x4*)(qp1 + ch * 32 + 4);
            u.d[0] = pk2(f0[0] * QSC, f0[1] * QSC);
            u.d[1] = pk2(f0[2] * QSC, f0[3] * QSC);
            u.d[2] = pk2(f1[0] * QSC, f1[1] * QSC);
            u.d[3] = pk2(f1[2] * QSC, f1[3] * QSC);
            aq1[ch] = u.b;
        }
    }

    f32x4 acc0[4] = {}, acc1[4] = {};
    f32x4 lrow0 = {}, lrow1 = {};

    // pipeline prologue: 2-deep prefetch (8 loads/wave outstanding)
    stage(0, 0);
    stage(1, 1);                           // ntl >= 2 always

    int cb = 0, sb = 2;                    // compute buf, stage buf (= cb+2 mod 3)
    for (int t = 0; t < ntl; ++t) {
        const int k0 = t * KVB;
        // counted vmcnt: wait own 4 loads of tile t; t+1's 4 stay in flight
        if (t + 1 < ntl) asm volatile("s_waitcnt vmcnt(4)" ::: "memory");
        else             asm volatile("s_waitcnt vmcnt(0)" ::: "memory");
        __builtin_amdgcn_s_barrier();

        {
            const bool live0 = (k0 <= wg0 + 15);   // group1 live in all epochs
            const unsigned short* Kc = &Kl[cb][0];
            const unsigned short* Vc = &Vl[cb][0];

            // ---- swapped QK^T: D[kk][q]; K reads shared by both q-groups ----
            __builtin_amdgcn_s_setprio(1);
            f32x4 s0[4], s1[4];
            #pragma unroll
            for (int nt = 0; nt < 4; ++nt) {
                const int row = nt * 16 + l15;
                const unsigned rb = (unsigned)row * 64, sw = (unsigned)((row & 7) << 3);
                U8 ak0, ak1;
                ak0.u = *(const u16x8*)&Kc[rb + ((unsigned)(l4 * 8) ^ sw)];
                ak1.u = *(const u16x8*)&Kc[rb + ((unsigned)(32 + l4 * 8) ^ sw)];
                if (live0) {
                    f32x4 z = {};
                    z = __builtin_amdgcn_mfma_f32_16x16x32_bf16(ak0.b, aq0[0], z, 0, 0, 0);
                    s0[nt] = __builtin_amdgcn_mfma_f32_16x16x32_bf16(ak1.b, aq0[1], z, 0, 0, 0);
                }
                f32x4 z1 = {};
                z1 = __builtin_amdgcn_mfma_f32_16x16x32_bf16(ak0.b, aq1[0], z1, 0, 0, 0);
                s1[nt] = __builtin_amdgcn_mfma_f32_16x16x32_bf16(ak1.b, aq1[1], z1, 0, 0, 0);
            }
            __builtin_amdgcn_s_setprio(0);

            // ---- causal mask (per-group diagonal region) ----
            if (live0 && (k0 + KVB - 1 > wg0)) {
                #pragma unroll
                for (int nt = 0; nt < 4; ++nt)
                    #pragma unroll
                    for (int r = 0; r < 4; ++r)
                        if (k0 + nt * 16 + l4 * 4 + r > qg0) s0[nt][r] = -INFINITY;
            }
            if (k0 + KVB - 1 > wg1) {
                #pragma unroll
                for (int nt = 0; nt < 4; ++nt)
                    #pragma unroll
                    for (int r = 0; r < 4; ++r)
                        if (k0 + nt * 16 + l4 * 4 + r > qg1) s1[nt][r] = -INFINITY;
            }

            // ---- P = exp2(s) packed into slot-permuted A-frags (lane-local) ----
            U4 u00, u01, u10, u11;
            if (live0) {
                u00.d[0] = pk2(exp2f(s0[0][0]), exp2f(s0[0][1]));
                u00.d[1] = pk2(exp2f(s0[0][2]), exp2f(s0[0][3]));
                u00.d[2] = pk2(exp2f(s0[1][0]), exp2f(s0[1][1]));
                u00.d[3] = pk2(exp2f(s0[1][2]), exp2f(s0[1][3]));
                u01.d[0] = pk2(exp2f(s0[2][0]), exp2f(s0[2][1]));
                u01.d[1] = pk2(exp2f(s0[2][2]), exp2f(s0[2][3]));
                u01.d[2] = pk2(exp2f(s0[3][0]), exp2f(s0[3][1]));
                u01.d[3] = pk2(exp2f(s0[3][2]), exp2f(s0[3][3]));
            }
            u10.d[0] = pk2(exp2f(s1[0][0]), exp2f(s1[0][1]));
            u10.d[1] = pk2(exp2f(s1[0][2]), exp2f(s1[0][3]));
            u10.d[2] = pk2(exp2f(s1[1][0]), exp2f(s1[1][1]));
            u10.d[3] = pk2(exp2f(s1[1][2]), exp2f(s1[1][3]));
            u11.d[0] = pk2(exp2f(s1[2][0]), exp2f(s1[2][1]));
            u11.d[1] = pk2(exp2f(s1[2][2]), exp2f(s1[2][3]));
            u11.d[2] = pk2(exp2f(s1[3][0]), exp2f(s1[3][1]));
            u11.d[3] = pk2(exp2f(s1[3][2]), exp2f(s1[3][3]));

            // ---- PV + row-sum; V reads shared by both q-groups ----
            __builtin_amdgcn_s_setprio(1);
            if (live0) {
                lrow0 = __builtin_amdgcn_mfma_f32_16x16x32_bf16(u00.b, ones.b, lrow0, 0, 0, 0);
                lrow0 = __builtin_amdgcn_mfma_f32_16x16x32_bf16(u01.b, ones.b, lrow0, 0, 0, 0);
            }
            lrow1 = __builtin_amdgcn_mfma_f32_16x16x32_bf16(u10.b, ones.b, lrow1, 0, 0, 0);
            lrow1 = __builtin_amdgcn_mfma_f32_16x16x32_bf16(u11.b, ones.b, lrow1, 0, 0, 0);
            #pragma unroll
            for (int nt = 0; nt < 4; ++nt) {
                const int row = nt * 16 + l15;
                const unsigned rb = (unsigned)row * 64, sw = (unsigned)((row & 7) << 3);
                U8 vb0, vb1;
                vb0.u = *(const u16x8*)&Vc[rb + ((unsigned)(l4 * 8) ^ sw)];
                vb1.u = *(const u16x8*)&Vc[rb + ((unsigned)(32 + l4 * 8) ^ sw)];
                if (live0) {
                    acc0[nt] = __builtin_amdgcn_mfma_f32_16x16x32_bf16(u00.b, vb0.b, acc0[nt], 0, 0, 0);
                    acc0[nt] = __builtin_amdgcn_mfma_f32_16x16x32_bf16(u01.b, vb1.b, acc0[nt], 0, 0, 0);
                }
                acc1[nt] = __builtin_amdgcn_mfma_f32_16x16x32_bf16(u10.b, vb0.b, acc1[nt], 0, 0, 0);
                acc1[nt] = __builtin_amdgcn_mfma_f32_16x16x32_bf16(u11.b, vb1.b, acc1[nt], 0, 0, 0);
            }
            __builtin_amdgcn_s_setprio(0);
        }

        // stage tile t+2 into buf sb (= last read at tile t-1; all its readers
        // passed this iteration's barrier before any wave reaches here)
        if (t + 2 < ntl) stage(sb, t + 2);
        cb = (cb == 2) ? 0 : cb + 1;
        sb = (sb == 2) ? 0 : sb + 1;
    }

    // ---- epilogue: O = acc / lrow (row layout, no shuffles) ----
    #pragma unroll
    for (int r = 0; r < 4; ++r) {
        const float inv0 = 1.f / lrow0[r];
        const float inv1 = 1.f / lrow1[r];
        float* op0 = O + qbase + (size_t)(wg0 + l4 * 4 + r) * DH + l15;
        float* op1 = O + qbase + (size_t)(wg1 + l4 * 4 + r) * DH + l15;
        #pragma unroll
        for (int nt = 0; nt < 4; ++nt) {
            op0[nt * 16] = acc0[nt][r] * inv0;
            op1[nt * 16] = acc1[nt][r] * inv1;
        }
    }
}

// ---------------- fallback (round-4 kernel, used if ws too small) ----------------
#define QBLK4 128
#define KPAD 72
#define NQT4  (SLEN/QBLK4)
#define NPAIR4 (NQT4/2)

extern "C" __global__ __launch_bounds__(256)
void fa_fwd_causal(const float* __restrict__ Q, const float* __restrict__ K,
                   const float* __restrict__ V, float* __restrict__ O)
{
    const int tid  = threadIdx.x;
    const int lane = tid & 63;
    const int w    = tid >> 6;
    const int l15  = lane & 15;
    const int l4   = lane >> 4;

    const int bid  = (int)blockIdx.x;
    const int work = (bid & 7) * (NPAIR4 * NHEAD / 8) + (bid >> 3);
    const int head = work >> 4;
    const int pr   = work & (NPAIR4 - 1);
    const size_t base = (size_t)head * SLEN * DH;

    __shared__ unsigned short Kl[2][KVB * KPAD];
    __shared__ unsigned short Vt[2][DH * KPAD];
    __shared__ unsigned short Plds[4][16 * KPAD];

    const float QSC = 0.125f * 1.44269504088896340736f;
    const int krow = tid >> 2,        kc0 = (tid & 3) * 16;
    const int vd0  = (tid >> 4) * 4,  vk0 = (tid & 15) * 4;

    #pragma unroll 1
    for (int ph = 0; ph < 2; ++ph) {
        const int qt  = ph ? (NQT4 - 1 - pr) : pr;
        const int q0  = qt * QBLK4;
        const int ntl = 2 * qt + 2;
        const int qwave = q0 + w * 32;

        bf16x8 aq[2][2];
        #pragma unroll
        for (int set = 0; set < 2; ++set) {
            const int qr = q0 + w * 32 + set * 16 + l15;
            const float* qp = Q + base + (size_t)qr * DH + l4 * 8;
            #pragma unroll
            for (int ch = 0; ch < 2; ++ch) {
                f32x4 f0 = *(const f32x4*)(qp + ch * 32);
                f32x4 f1 = *(const f32x4*)(qp + ch * 32 + 4);
                U8 u;
                #pragma unroll
                for (int j = 0; j < 4; ++j) { u.u[j] = f2bf(f0[j] * QSC); u.u[4 + j] = f2bf(f1[j] * QSC); }
                aq[set][ch] = u.b;
            }
        }

        f32x4 acc[2][4] = {};
        float mrun[2] = { -INFINITY, -INFINITY };
        float lrun[2] = { 0.f, 0.f };
        f32x4 kreg[4], vreg[4];

        auto g_load = [&](int t) {
            const float* kp = K + base + (size_t)(t * KVB + krow) * DH + kc0;
            #pragma unroll
            for (int i = 0; i < 4; ++i) kreg[i] = *(const f32x4*)(kp + i * 4);
            const float* vp = V + base + (size_t)(t * KVB + vk0) * DH + vd0;
            #pragma unroll
            for (int i = 0; i < 4; ++i) vreg[i] = *(const f32x4*)(vp + (size_t)i * DH);
        };
        auto s_write = [&](int c) {
            unsigned short tmp[16];
            #pragma unroll
            for (int i = 0; i < 4; ++i)
                #pragma unroll
                for (int j = 0; j < 4; ++j) tmp[i * 4 + j] = f2bf(kreg[i][j]);
            unsigned short* kd = &Kl[c][krow * KPAD + kc0];
            *(u16x8*)kd       = *(u16x8*)&tmp[0];
            *(u16x8*)(kd + 8) = *(u16x8*)&tmp[8];
            #pragma unroll
            for (int i = 0; i < 4; ++i) {
                u16x4 pk;
                pk[0] = f2bf(vreg[0][i]); pk[1] = f2bf(vreg[1][i]);
                pk[2] = f2bf(vreg[2][i]); pk[3] = f2bf(vreg[3][i]);
                *(u16x4*)&Vt[c][(vd0 + i) * KPAD + vk0] = pk;
            }
        };

        g_load(0); s_write(0); g_load(1);
        __syncthreads();

        for (int t = 0; t < ntl; ++t) {
            const int c  = t & 1;
            const int k0 = t * KVB;
            if (t + 1 < ntl) { s_write(c ^ 1); if (t + 2 < ntl) g_load(t + 2); }

            if (k0 <= qwave + 31) {
                #pragma unroll
                for (int set = 0; set < 2; ++set) {
                    const int qs0 = qwave + set * 16;
                    if (k0 > qs0 + 15) continue;
                    const int q = qs0 + l15;

                    f32x4 s[4];
                    #pragma unroll
                    for (int nt = 0; nt < 4; ++nt) {
                        U8 ak0, ak1;
                        ak0.u = *(const u16x8*)&Kl[c][(nt*16 + l15) * KPAD + l4*8];
                        ak1.u = *(const u16x8*)&Kl[c][(nt*16 + l15) * KPAD + 32 + l4*8];
                        f32x4 z = {};
                        z = __builtin_amdgcn_mfma_f32_16x16x32_bf16(ak0.b, aq[set][0], z, 0, 0, 0);
                        z = __builtin_amdgcn_mfma_f32_16x16x32_bf16(ak1.b, aq[set][1], z, 0, 0, 0);
                        s[nt] = z;
                    }
                    if (k0 + KVB - 1 > qs0) {
                        #pragma unroll
                        for (int nt = 0; nt < 4; ++nt)
                            #pragma unroll
                            for (int r = 0; r < 4; ++r)
                                if (k0 + nt*16 + l4*4 + r > q) s[nt][r] = -INFINITY;
                    }
                    float mx = s[0][0];
                    #pragma unroll
                    for (int nt = 0; nt < 4; ++nt)
                        #pragma unroll
                        for (int r = 0; r < 4; ++r)
                            if (!(nt == 0 && r == 0)) mx = fmaxf(mx, s[nt][r]);
                    mx = fmaxf(mx, __shfl_xor(mx, 16));
                    mx = fmaxf(mx, __shfl_xor(mx, 32));
                    float mn = fmaxf(mrun[set], mx);
                    float fr = exp2f(mrun[set] - mn);
                    mrun[set] = mn;
                    float p[4][4];
                    float rs = 0.f;
                    #pragma unroll
                    for (int nt = 0; nt < 4; ++nt)
                        #pragma unroll
                        for (int r = 0; r < 4; ++r) {
                            float e = exp2f(s[nt][r] - mn);
                            p[nt][r] = e; rs += e;
                        }
                    rs += __shfl_xor(rs, 16);
                    rs += __shfl_xor(rs, 32);
                    lrun[set] = lrun[set] * fr + rs;

                    unsigned short* Pw = &Plds[w][0];
                    #pragma unroll
                    for (int nt = 0; nt < 4; ++nt) {
                        u16x4 pk;
                        pk[0] = f2bf(p[nt][0]); pk[1] = f2bf(p[nt][1]);
                        pk[2] = f2bf(p[nt][2]); pk[3] = f2bf(p[nt][3]);
                        *(u16x4*)&Pw[l15 * KPAD + nt*16 + l4*4] = pk;
                    }
                    #pragma unroll
                    for (int r = 0; r < 4; ++r) {
                        float frr = __shfl(fr, l4*4 + r);
                        #pragma unroll
                        for (int nt = 0; nt < 4; ++nt) acc[set][nt][r] *= frr;
                    }
                    asm volatile("s_waitcnt lgkmcnt(0)" ::: "memory");
                    __builtin_amdgcn_sched_barrier(0);
                    U8 pa0, pa1;
                    pa0.u = *(const u16x8*)&Pw[l15 * KPAD + l4*8];
                    pa1.u = *(const u16x8*)&Pw[l15 * KPAD + 32 + l4*8];
                    #pragma unroll
                    for (int nt = 0; nt < 4; ++nt) {
                        U8 vb0, vb1;
                        vb0.u = *(const u16x8*)&Vt[c][(nt*16 + l15) * KPAD + l4*8];
                        vb1.u = *(const u16x8*)&Vt[c][(nt*16 + l15) * KPAD + 32 + l4*8];
                        acc[set][nt] = __builtin_amdgcn_mfma_f32_16x16x32_bf16(pa0.b, vb0.b, acc[set][nt], 0, 0, 0);
                        acc[set][nt] = __builtin_amdgcn_mfma_f32_16x16x32_bf16(pa1.b, vb1.b, acc[set][nt], 0, 0, 0);
                    }
                }
            }
            __syncthreads();
        }
        #pragma unroll
        for (int set = 0; set < 2; ++set) {
            float inv = 1.f / lrun[set];
            #pragma unroll
            for (int r = 0; r < 4; ++r) {
                float invr = __shfl(inv, l4*4 + r);
                const int qrow = q0 + w*32 + set*16 + l4*4 + r;
                float* op = O + base + (size_t)qrow * DH + l15;
                #pragma unroll
                for (int nt = 0; nt < 4; ++nt)
                    op[nt*16] = acc[set][nt][r] * invr;
            }
        }
        __syncthreads();
    }
}

extern "C" void kernel_launch(void* const* d_in, const int* in_sizes, int n_in,
                              void* d_out, int out_size, void* d_ws, size_t ws_size,
                              hipStream_t stream) {
    (void)in_sizes; (void)n_in; (void)out_size;
    const float* q = (const float*)d_in[0];
    const float* k = (const float*)d_in[1];
    const float* v = (const float*)d_in[2];
    float* o = (float*)d_out;

    const size_t kv_elems = (size_t)NHEAD * 64 * TILE_E;
    const size_t need = 2 * kv_elems * sizeof(unsigned short);
    if (ws_size >= need) {
        unsigned short* Kb = (unsigned short*)d_ws;
        unsigned short* Vtw = Kb + kv_elems;
        prep_kv<<<dim3(NHEAD * 64, 2), 512, 0, stream>>>(k, v, Kb, Vtw);
        fa_fwd_v20<<<dim3(NQT * NHEAD), 256, 0, stream>>>(q, o, Kb, Vtw);
    } else {
        fa_fwd_causal<<<dim3(NPAIR4 * NHEAD), 256, 0, stream>>>(q, k, v, o);
    }
}

// Round 21
// 126.785 us; speedup vs baseline: 1.1922x; 1.0226x over previous
//
#include <hip/hip_runtime.h>
#include <hip/hip_bf16.h>
#include <math.h>

#define SLEN 4096
#define DH   64
#define KVB  64
#define NHEAD 32
#define QBLK 128
#define NQT   (SLEN / QBLK)  // 32
#define TILE_E (KVB * DH)    // 4096 elems per staged tile

typedef float  f32x4 __attribute__((ext_vector_type(4)));
typedef short  bf16x8 __attribute__((ext_vector_type(8)));
typedef unsigned short u16x8 __attribute__((ext_vector_type(8)));
typedef unsigned short u16x4 __attribute__((ext_vector_type(4)));
union U8 { u16x8 u; bf16x8 b; };
union U4 { unsigned d[4]; bf16x8 b; };

__device__ inline unsigned short f2bf(float f) {
    return __builtin_bit_cast(unsigned short, __float2bfloat16(f));
}
__device__ inline unsigned pk2(float lo, float hi_) {   // v_cvt_pk_bf16_f32
    return (unsigned)f2bf(lo) | ((unsigned)f2bf(hi_) << 16);
}

__device__ inline void gload16(const unsigned short* g, unsigned short* l) {
    __builtin_amdgcn_global_load_lds(
        (const __attribute__((address_space(1))) void*)g,
        (__attribute__((address_space(3))) void*)l, 16, 0, 0);
}

// ---------------- pre-pass: f32 K,V -> bf16 swizzled tile layout in ws ----------
// K tile (4096 bf16): elem = row*64 + (d ^ ((row&7)<<3)),      row = kv, d = dim.
// V tile (4096 bf16): elem = d*64 + (pos(kk) ^ ((d&7)<<3)),    rows = dim.
//   pos(kk) = (kk>>5)*32 + ((kk&15)>>2)*8 + ((kk>>4)&1)*4 + (kk&3)
//   -> lane l4's b128 at pos l4*8 covers kk {l4*4+j} then {16+l4*4+j}: matches
//      the in-register P fragment slot order (A/B slot permutations agree).
extern "C" __global__ __launch_bounds__(512)
void prep_kv(const float* __restrict__ K, const float* __restrict__ V,
             unsigned short* __restrict__ Kb, unsigned short* __restrict__ Vt)
{
    const int tile = blockIdx.x & 63;
    const int head = blockIdx.x >> 6;
    const size_t gbase = (size_t)head * SLEN * DH + (size_t)tile * KVB * DH;
    const size_t tbase = ((size_t)head * 64 + tile) * TILE_E;
    const int tid = threadIdx.x;
    if (blockIdx.y == 0) {
        const int row = tid >> 3, d0 = (tid & 7) * 8;
        const float* src = K + gbase + (size_t)row * DH + d0;
        f32x4 a = *(const f32x4*)src, b = *(const f32x4*)(src + 4);
        u16x8 o;
        #pragma unroll
        for (int j = 0; j < 4; ++j) { o[j] = f2bf(a[j]); o[4 + j] = f2bf(b[j]); }
        *(u16x8*)&Kb[tbase + row * 64 + ((unsigned)d0 ^ ((row & 7) << 3))] = o;
    } else {
        const int kk = tid & 63, d0 = (tid >> 6) * 8;
        const int pos = ((kk >> 5) << 5) | (((kk & 15) >> 2) << 3)
                      | (((kk >> 4) & 1) << 2) | (kk & 3);
        const float* src = V + gbase + (size_t)kk * DH + d0;
        f32x4 a = *(const f32x4*)src, b = *(const f32x4*)(src + 4);
        #pragma unroll
        for (int j = 0; j < 8; ++j) {
            const int d = d0 + j;
            const float x = (j < 4) ? a[j] : b[j - 4];
            Vt[tbase + d * 64 + ((unsigned)pos ^ ((d & 7) << 3))] = f2bf(x);
        }
    }
}

// ---- main v21: v18 + epoch pipeline: QK^T(t) || PV(t-1), P carried in VGPRs ----
extern "C" __global__ __launch_bounds__(256, 3)
void fa_fwd_v21(const float* __restrict__ Q, float* __restrict__ O,
                const unsigned short* __restrict__ Kb,
                const unsigned short* __restrict__ Vt)
{
    const int tid  = threadIdx.x;
    const int lane = tid & 63;
    const int w    = tid >> 6;
    const int l15  = lane & 15;
    const int l4   = lane >> 4;

    // residency-balanced qt map (v16-proven)
    const int bid  = (int)blockIdx.x;
    const int i32  = bid >> 5;
    const int qt   = (i32 < 16) ? (2 * i32) : (63 - 2 * i32);
    const int head = bid & 31;                 // 4 heads/XCD -> KV L2-resident
    const size_t qbase  = (size_t)head * SLEN * DH;
    const size_t kvbase = (size_t)head * 64 * TILE_E;

    __shared__ __align__(16) unsigned short Kl[3][TILE_E];   // 8 KB each
    __shared__ __align__(16) unsigned short Vl[3][TILE_E];   // 8 KB each

    const float QSC = 0.125f * 1.44269504088896340736f;   // 1/sqrt(64)*log2(e)

    U8 ones;
    #pragma unroll
    for (int j = 0; j < 8; ++j) ones.u[j] = 0x3F80;       // bf16 1.0

    const unsigned short* ksrc = Kb + kvbase;
    const unsigned short* vsrc = Vt + kvbase;

    const int q0   = qt * QBLK;
    const int ntl  = 2 * qt + 2;
    // interleaved q-groups (v18): group1 live for QK^T in all epochs
    const int wg0  = q0 + w * 16;
    const int wg1  = q0 + 64 + w * 16;
    const int qg0  = wg0 + l15;
    const int qg1  = wg1 + l15;

    auto stageK = [&](int b, int t) {
        const size_t toff = (size_t)t * TILE_E;
        const int ib = w * 2;
        gload16(ksrc + toff + ib * 512 + lane * 8,       &Kl[b][ib * 512]);
        gload16(ksrc + toff + (ib + 1) * 512 + lane * 8, &Kl[b][(ib + 1) * 512]);
    };
    auto stageV = [&](int b, int t) {
        const size_t toff = (size_t)t * TILE_E;
        const int ib = w * 2;
        gload16(vsrc + toff + ib * 512 + lane * 8,       &Vl[b][ib * 512]);
        gload16(vsrc + toff + (ib + 1) * 512 + lane * 8, &Vl[b][(ib + 1) * 512]);
    };

    // prologue (issue order matters for vmcnt): K0, V0, K1
    stageK(0, 0);
    stageV(0, 0);
    stageK(1, 1);                          // ntl >= 2 always

    // Q fragments for both groups (B-operand: lane holds Q[q][d = l4*8 + j])
    bf16x8 aq0[2], aq1[2];
    {
        const float* qp0 = Q + qbase + (size_t)qg0 * DH + l4 * 8;
        const float* qp1 = Q + qbase + (size_t)qg1 * DH + l4 * 8;
        #pragma unroll
        for (int ch = 0; ch < 2; ++ch) {
            f32x4 f0 = *(const f32x4*)(qp0 + ch * 32);
            f32x4 f1 = *(const f32x4*)(qp0 + ch * 32 + 4);
            U4 u;
            u.d[0] = pk2(f0[0] * QSC, f0[1] * QSC);
            u.d[1] = pk2(f0[2] * QSC, f0[3] * QSC);
            u.d[2] = pk2(f1[0] * QSC, f1[1] * QSC);
            u.d[3] = pk2(f1[2] * QSC, f1[3] * QSC);
            aq0[ch] = u.b;
            f0 = *(const f32x4*)(qp1 + ch * 32);
            f1 = *(const f32x4*)(qp1 + ch * 32 + 4);
            u.d[0] = pk2(f0[0] * QSC, f0[1] * QSC);
            u.d[1] = pk2(f0[2] * QSC, f0[3] * QSC);
            u.d[2] = pk2(f1[0] * QSC, f1[1] * QSC);
            u.d[3] = pk2(f1[2] * QSC, f1[3] * QSC);
            aq1[ch] = u.b;
        }
    }

    f32x4 acc0[4] = {}, acc1[4] = {};
    f32x4 lrow0 = {}, lrow1 = {};
    U4 pu00, pu01, pu10, pu11;             // carried P fragments (prev tile)
    bool prevL0 = false;

    for (int t = 0; t < ntl; ++t) {
        const int k0 = t * KVB;
        // queue at top: [V(t-1),K(t),V(t),K(t+1)] -> steady vmcnt(4);
        // last epoch K(t+1) absent -> vmcnt(2)
        if (t + 1 < ntl) asm volatile("s_waitcnt vmcnt(4)" ::: "memory");
        else             asm volatile("s_waitcnt vmcnt(2)" ::: "memory");
        __builtin_amdgcn_s_barrier();

        const unsigned short* Kc = &Kl[t % 3][0];
        const unsigned short* Vc = &Vl[(t + 2) % 3][0];   // = (t-1)%3, t>=1
        const bool live0 = (k0 <= wg0 + 15);

        // ---- QK^T(t): D[kk][q]; K reads shared by both q-groups ----
        __builtin_amdgcn_s_setprio(1);
        f32x4 s0[4], s1[4];
        #pragma unroll
        for (int nt = 0; nt < 4; ++nt) {
            const int row = nt * 16 + l15;
            const unsigned rb = (unsigned)row * 64, sw = (unsigned)((row & 7) << 3);
            U8 ak0, ak1;
            ak0.u = *(const u16x8*)&Kc[rb + ((unsigned)(l4 * 8) ^ sw)];
            ak1.u = *(const u16x8*)&Kc[rb + ((unsigned)(32 + l4 * 8) ^ sw)];
            if (live0) {
                f32x4 z = {};
                z = __builtin_amdgcn_mfma_f32_16x16x32_bf16(ak0.b, aq0[0], z, 0, 0, 0);
                s0[nt] = __builtin_amdgcn_mfma_f32_16x16x32_bf16(ak1.b, aq0[1], z, 0, 0, 0);
            }
            f32x4 z1 = {};
            z1 = __builtin_amdgcn_mfma_f32_16x16x32_bf16(ak0.b, aq1[0], z1, 0, 0, 0);
            s1[nt] = __builtin_amdgcn_mfma_f32_16x16x32_bf16(ak1.b, aq1[1], z1, 0, 0, 0);
        }

        // ---- PV(t-1): independent of QK^T(t); fills its latency shadow ----
        if (t > 0) {
            if (prevL0) {
                lrow0 = __builtin_amdgcn_mfma_f32_16x16x32_bf16(pu00.b, ones.b, lrow0, 0, 0, 0);
                lrow0 = __builtin_amdgcn_mfma_f32_16x16x32_bf16(pu01.b, ones.b, lrow0, 0, 0, 0);
            }
            lrow1 = __builtin_amdgcn_mfma_f32_16x16x32_bf16(pu10.b, ones.b, lrow1, 0, 0, 0);
            lrow1 = __builtin_amdgcn_mfma_f32_16x16x32_bf16(pu11.b, ones.b, lrow1, 0, 0, 0);
            #pragma unroll
            for (int nt = 0; nt < 4; ++nt) {
                const int row = nt * 16 + l15;
                const unsigned rb = (unsigned)row * 64, sw = (unsigned)((row & 7) << 3);
                U8 vb0, vb1;
                vb0.u = *(const u16x8*)&Vc[rb + ((unsigned)(l4 * 8) ^ sw)];
                vb1.u = *(const u16x8*)&Vc[rb + ((unsigned)(32 + l4 * 8) ^ sw)];
                if (prevL0) {
                    acc0[nt] = __builtin_amdgcn_mfma_f32_16x16x32_bf16(pu00.b, vb0.b, acc0[nt], 0, 0, 0);
                    acc0[nt] = __builtin_amdgcn_mfma_f32_16x16x32_bf16(pu01.b, vb1.b, acc0[nt], 0, 0, 0);
                }
                acc1[nt] = __builtin_amdgcn_mfma_f32_16x16x32_bf16(pu10.b, vb0.b, acc1[nt], 0, 0, 0);
                acc1[nt] = __builtin_amdgcn_mfma_f32_16x16x32_bf16(pu11.b, vb1.b, acc1[nt], 0, 0, 0);
            }
        }
        __builtin_amdgcn_s_setprio(0);

        // ---- causal mask tile t (per-group diagonal region) ----
        if (live0 && (k0 + KVB - 1 > wg0)) {
            #pragma unroll
            for (int nt = 0; nt < 4; ++nt)
                #pragma unroll
                for (int r = 0; r < 4; ++r)
                    if (k0 + nt * 16 + l4 * 4 + r > qg0) s0[nt][r] = -INFINITY;
        }
        if (k0 + KVB - 1 > wg1) {
            #pragma unroll
            for (int nt = 0; nt < 4; ++nt)
                #pragma unroll
                for (int r = 0; r < 4; ++r)
                    if (k0 + nt * 16 + l4 * 4 + r > qg1) s1[nt][r] = -INFINITY;
        }

        // ---- P(t) = exp2(s) packed into carried slot-permuted A-frags ----
        if (live0) {
            pu00.d[0] = pk2(exp2f(s0[0][0]), exp2f(s0[0][1]));
            pu00.d[1] = pk2(exp2f(s0[0][2]), exp2f(s0[0][3]));
            pu00.d[2] = pk2(exp2f(s0[1][0]), exp2f(s0[1][1]));
            pu00.d[3] = pk2(exp2f(s0[1][2]), exp2f(s0[1][3]));
            pu01.d[0] = pk2(exp2f(s0[2][0]), exp2f(s0[2][1]));
            pu01.d[1] = pk2(exp2f(s0[2][2]), exp2f(s0[2][3]));
            pu01.d[2] = pk2(exp2f(s0[3][0]), exp2f(s0[3][1]));
            pu01.d[3] = pk2(exp2f(s0[3][2]), exp2f(s0[3][3]));
        }
        pu10.d[0] = pk2(exp2f(s1[0][0]), exp2f(s1[0][1]));
        pu10.d[1] = pk2(exp2f(s1[0][2]), exp2f(s1[0][3]));
        pu10.d[2] = pk2(exp2f(s1[1][0]), exp2f(s1[1][1]));
        pu10.d[3] = pk2(exp2f(s1[1][2]), exp2f(s1[1][3]));
        pu11.d[0] = pk2(exp2f(s1[2][0]), exp2f(s1[2][1]));
        pu11.d[1] = pk2(exp2f(s1[2][2]), exp2f(s1[2][3]));
        pu11.d[2] = pk2(exp2f(s1[3][0]), exp2f(s1[3][1]));
        pu11.d[3] = pk2(exp2f(s1[3][2]), exp2f(s1[3][3]));
        prevL0 = live0;

        // ---- stage: V 1-deep, K 2-deep (targets freed at barrier above) ----
        if (t + 1 < ntl) stageV((t + 1) % 3, t + 1);
        if (t + 2 < ntl) stageK((t + 2) % 3, t + 2);
    }

    // ---- tail: PV(ntl-1); own V loads drained, barrier for all waves' ----
    asm volatile("s_waitcnt vmcnt(0)" ::: "memory");
    __builtin_amdgcn_s_barrier();
    {
        const unsigned short* Vc = &Vl[(ntl + 2) % 3][0];   // (ntl-1)%3
        if (prevL0) {
            lrow0 = __builtin_amdgcn_mfma_f32_16x16x32_bf16(pu00.b, ones.b, lrow0, 0, 0, 0);
            lrow0 = __builtin_amdgcn_mfma_f32_16x16x32_bf16(pu01.b, ones.b, lrow0, 0, 0, 0);
        }
        lrow1 = __builtin_amdgcn_mfma_f32_16x16x32_bf16(pu10.b, ones.b, lrow1, 0, 0, 0);
        lrow1 = __builtin_amdgcn_mfma_f32_16x16x32_bf16(pu11.b, ones.b, lrow1, 0, 0, 0);
        #pragma unroll
        for (int nt = 0; nt < 4; ++nt) {
            const int row = nt * 16 + l15;
            const unsigned rb = (unsigned)row * 64, sw = (unsigned)((row & 7) << 3);
            U8 vb0, vb1;
            vb0.u = *(const u16x8*)&Vc[rb + ((unsigned)(l4 * 8) ^ sw)];
            vb1.u = *(const u16x8*)&Vc[rb + ((unsigned)(32 + l4 * 8) ^ sw)];
            if (prevL0) {
                acc0[nt] = __builtin_amdgcn_mfma_f32_16x16x32_bf16(pu00.b, vb0.b, acc0[nt], 0, 0, 0);
                acc0[nt] = __builtin_amdgcn_mfma_f32_16x16x32_bf16(pu01.b, vb1.b, acc0[nt], 0, 0, 0);
            }
            acc1[nt] = __builtin_amdgcn_mfma_f32_16x16x32_bf16(pu10.b, vb0.b, acc1[nt], 0, 0, 0);
            acc1[nt] = __builtin_amdgcn_mfma_f32_16x16x32_bf16(pu11.b, vb1.b, acc1[nt], 0, 0, 0);
        }
    }

    // ---- epilogue: O = acc / lrow (row layout, no shuffles) ----
    #pragma unroll
    for (int r = 0; r < 4; ++r) {
        const float inv0 = 1.f / lrow0[r];
        const float inv1 = 1.f / lrow1[r];
        float* op0 = O + qbase + (size_t)(wg0 + l4 * 4 + r) * DH + l15;
        float* op1 = O + qbase + (size_t)(wg1 + l4 * 4 + r) * DH + l15;
        #pragma unroll
        for (int nt = 0; nt < 4; ++nt) {
            op0[nt * 16] = acc0[nt][r] * inv0;
            op1[nt * 16] = acc1[nt][r] * inv1;
        }
    }
}

// ---------------- fallback (round-4 kernel, used if ws too small) ----------------
#define QBLK4 128
#define KPAD 72
#define NQT4  (SLEN/QBLK4)
#define NPAIR4 (NQT4/2)

extern "C" __global__ __launch_bounds__(256)
void fa_fwd_causal(const float* __restrict__ Q, const float* __restrict__ K,
                   const float* __restrict__ V, float* __restrict__ O)
{
    const int tid  = threadIdx.x;
    const int lane = tid & 63;
    const int w    = tid >> 6;
    const int l15  = lane & 15;
    const int l4   = lane >> 4;

    const int bid  = (int)blockIdx.x;
    const int work = (bid & 7) * (NPAIR4 * NHEAD / 8) + (bid >> 3);
    const int head = work >> 4;
    const int pr   = work & (NPAIR4 - 1);
    const size_t base = (size_t)head * SLEN * DH;

    __shared__ unsigned short Kl[2][KVB * KPAD];
    __shared__ unsigned short Vt[2][DH * KPAD];
    __shared__ unsigned short Plds[4][16 * KPAD];

    const float QSC = 0.125f * 1.44269504088896340736f;
    const int krow = tid >> 2,        kc0 = (tid & 3) * 16;
    const int vd0  = (tid >> 4) * 4,  vk0 = (tid & 15) * 4;

    #pragma unroll 1
    for (int ph = 0; ph < 2; ++ph) {
        const int qt  = ph ? (NQT4 - 1 - pr) : pr;
        const int q0  = qt * QBLK4;
        const int ntl = 2 * qt + 2;
        const int qwave = q0 + w * 32;

        bf16x8 aq[2][2];
        #pragma unroll
        for (int set = 0; set < 2; ++set) {
            const int qr = q0 + w * 32 + set * 16 + l15;
            const float* qp = Q + base + (size_t)qr * DH + l4 * 8;
            #pragma unroll
            for (int ch = 0; ch < 2; ++ch) {
                f32x4 f0 = *(const f32x4*)(qp + ch * 32);
                f32x4 f1 = *(const f32x4*)(qp + ch * 32 + 4);
                U8 u;
                #pragma unroll
                for (int j = 0; j < 4; ++j) { u.u[j] = f2bf(f0[j] * QSC); u.u[4 + j] = f2bf(f1[j] * QSC); }
                aq[set][ch] = u.b;
            }
        }

        f32x4 acc[2][4] = {};
        float mrun[2] = { -INFINITY, -INFINITY };
        float lrun[2] = { 0.f, 0.f };
        f32x4 kreg[4], vreg[4];

        auto g_load = [&](int t) {
            const float* kp = K + base + (size_t)(t * KVB + krow) * DH + kc0;
            #pragma unroll
            for (int i = 0; i < 4; ++i) kreg[i] = *(const f32x4*)(kp + i * 4);
            const float* vp = V + base + (size_t)(t * KVB + vk0) * DH + vd0;
            #pragma unroll
            for (int i = 0; i < 4; ++i) vreg[i] = *(const f32x4*)(vp + (size_t)i * DH);
        };
        auto s_write = [&](int c) {
            unsigned short tmp[16];
            #pragma unroll
            for (int i = 0; i < 4; ++i)
                #pragma unroll
                for (int j = 0; j < 4; ++j) tmp[i * 4 + j] = f2bf(kreg[i][j]);
            unsigned short* kd = &Kl[c][krow * KPAD + kc0];
            *(u16x8*)kd       = *(u16x8*)&tmp[0];
            *(u16x8*)(kd + 8) = *(u16x8*)&tmp[8];
            #pragma unroll
            for (int i = 0; i < 4; ++i) {
                u16x4 pk;
                pk[0] = f2bf(vreg[0][i]); pk[1] = f2bf(vreg[1][i]);
                pk[2] = f2bf(vreg[2][i]); pk[3] = f2bf(vreg[3][i]);
                *(u16x4*)&Vt[c][(vd0 + i) * KPAD + vk0] = pk;
            }
        };

        g_load(0); s_write(0); g_load(1);
        __syncthreads();

        for (int t = 0; t < ntl; ++t) {
            const int c  = t & 1;
            const int k0 = t * KVB;
            if (t + 1 < ntl) { s_write(c ^ 1); if (t + 2 < ntl) g_load(t + 2); }

            if (k0 <= qwave + 31) {
                #pragma unroll
                for (int set = 0; set < 2; ++set) {
                    const int qs0 = qwave + set * 16;
                    if (k0 > qs0 + 15) continue;
                    const int q = qs0 + l15;

                    f32x4 s[4];
                    #pragma unroll
                    for (int nt = 0; nt < 4; ++nt) {
                        U8 ak0, ak1;
                        ak0.u = *(const u16x8*)&Kl[c][(nt*16 + l15) * KPAD + l4*8];
                        ak1.u = *(const u16x8*)&Kl[c][(nt*16 + l15) * KPAD + 32 + l4*8];
                        f32x4 z = {};
                        z = __builtin_amdgcn_mfma_f32_16x16x32_bf16(ak0.b, aq[set][0], z, 0, 0, 0);
                        z = __builtin_amdgcn_mfma_f32_16x16x32_bf16(ak1.b, aq[set][1], z, 0, 0, 0);
                        s[nt] = z;
                    }
                    if (k0 + KVB - 1 > qs0) {
                        #pragma unroll
                        for (int nt = 0; nt < 4; ++nt)
                            #pragma unroll
                            for (int r = 0; r < 4; ++r)
                                if (k0 + nt*16 + l4*4 + r > q) s[nt][r] = -INFINITY;
                    }
                    float mx = s[0][0];
                    #pragma unroll
                    for (int nt = 0; nt < 4; ++nt)
                        #pragma unroll
                        for (int r = 0; r < 4; ++r)
                            if (!(nt == 0 && r == 0)) mx = fmaxf(mx, s[nt][r]);
                    mx = fmaxf(mx, __shfl_xor(mx, 16));
                    mx = fmaxf(mx, __shfl_xor(mx, 32));
                    float mn = fmaxf(mrun[set], mx);
                    float fr = exp2f(mrun[set] - mn);
                    mrun[set] = mn;
                    float p[4][4];
                    float rs = 0.f;
                    #pragma unroll
                    for (int nt = 0; nt < 4; ++nt)
                        #pragma unroll
                        for (int r = 0; r < 4; ++r) {
                            float e = exp2f(s[nt][r] - mn);
                            p[nt][r] = e; rs += e;
                        }
                    rs += __shfl_xor(rs, 16);
                    rs += __shfl_xor(rs, 32);
                    lrun[set] = lrun[set] * fr + rs;

                    unsigned short* Pw = &Plds[w][0];
                    #pragma unroll
                    for (int nt = 0; nt < 4; ++nt) {
                        u16x4 pk;
                        pk[0] = f2bf(p[nt][0]); pk[1] = f2bf(p[nt][1]);
                        pk[2] = f2bf(p[nt][2]); pk[3] = f2bf(p[nt][3]);
                        *(u16x4*)&Pw[l15 * KPAD + nt*16 + l4*4] = pk;
                    }
                    #pragma unroll
                    for (int r = 0; r < 4; ++r) {
                        float frr = __shfl(fr, l4*4 + r);
                        #pragma unroll
                        for (int nt = 0; nt < 4; ++nt) acc[set][nt][r] *= frr;
                    }
                    asm volatile("s_waitcnt lgkmcnt(0)" ::: "memory");
                    __builtin_amdgcn_sched_barrier(0);
                    U8 pa0, pa1;
                    pa0.u = *(const u16x8*)&Pw[l15 * KPAD + l4*8];
                    pa1.u = *(const u16x8*)&Pw[l15 * KPAD + 32 + l4*8];
                    #pragma unroll
                    for (int nt = 0; nt < 4; ++nt) {
                        U8 vb0, vb1;
                        vb0.u = *(const u16x8*)&Vt[c][(nt*16 + l15) * KPAD + l4*8];
                        vb1.u = *(const u16x8*)&Vt[c][(nt*16 + l15) * KPAD + 32 + l4*8];
                        acc[set][nt] = __builtin_amdgcn_mfma_f32_16x16x32_bf16(pa0.b, vb0.b, acc[set][nt], 0, 0, 0);
                        acc[set][nt] = __builtin_amdgcn_mfma_f32_16x16x32_bf16(pa1.b, vb1.b, acc[set][nt], 0, 0, 0);
                    }
                }
            }
            __syncthreads();
        }
        #pragma unroll
        for (int set = 0; set < 2; ++set) {
            float inv = 1.f / lrun[set];
            #pragma unroll
            for (int r = 0; r < 4; ++r) {
                float invr = __shfl(inv, l4*4 + r);
                const int qrow = q0 + w*32 + set*16 + l4*4 + r;
                float* op = O + base + (size_t)qrow * DH + l15;
                #pragma unroll
                for (int nt = 0; nt < 4; ++nt)
                    op[nt*16] = acc[set][nt][r] * invr;
            }
        }
        __syncthreads();
    }
}

extern "C" void kernel_launch(void* const* d_in, const int* in_sizes, int n_in,
                              void* d_out, int out_size, void* d_ws, size_t ws_size,
                              hipStream_t stream) {
    (void)in_sizes; (void)n_in; (void)out_size;
    const float* q = (const float*)d_in[0];
    const float* k = (const float*)d_in[1];
    const float* v = (const float*)d_in[2];
    float* o = (float*)d_out;

    const size_t kv_elems = (size_t)NHEAD * 64 * TILE_E;
    const size_t need = 2 * kv_elems * sizeof(unsigned short);
    if (ws_size >= need) {
        unsigned short* Kb = (unsigned short*)d_ws;
        unsigned short* Vtw = Kb + kv_elems;
        prep_kv<<<dim3(NHEAD * 64, 2), 512, 0, stream>>>(k, v, Kb, Vtw);
        fa_fwd_v21<<<dim3(NQT * NHEAD), 256, 0, stream>>>(q, o, Kb, Vtw);
    } else {
        fa_fwd_causal<<<dim3(NPAIR4 * NHEAD), 256, 0, stream>>>(q, k, v, o);
    }
}